// Round 8
// baseline (1925.831 us; speedup 1.0000x reference)
//
#include <hip/hip_runtime.h>

// RVQTokenizer: x[16,2048,256] f32, codebooks[4,1024,256] f32.
// Outputs (flat f32): quant[16,2048,256], indices[4,16,2048] (as float),
// 4 scalar losses (all = total vq_loss).
#define B_    16
#define T_    2048
#define D_    256
#define Q_    4
#define K_    1024
#define NTOK  (B_ * T_)            // 32768
#define QUANT_N (NTOK * D_)        // 8388608
#define IDX_N   (Q_ * NTOK)        // 131072
#define LOSS_OFF (QUANT_N + IDX_N) // 8519680
#define TPB   32                   // tokens per block
#define MARGIN 0.03f               // coarse-score ambiguity window (np-emulated rescore)

__device__ __forceinline__ bool lt2(float v, int k, float w, int m) {
  return v < w || (v == w && k < m);
}

// ---------------------------------------------------------------------------
// Bit-exact numpy emulation helpers.
//
// np.sum(v, axis=-1) for 256 contiguous f32 on an AVX512 host:
// pairwise_sum splits 256 -> two 128-halves. Each half (FLOAT_add AVX512F
// dispatch, nlanes=16): 8 vector accumulators loaded in ONE pass
// (r_j = v[base+16j .. +15]), vector tree ((r0+r1)+(r2+r3))+((r4+r5)+(r6+r7)),
// then _mm512_reduce_add_ps fold-in-half (l,l+8)(l,l+4)(l,l+2)(l,l+1).
// Halves combined with a single add.
template <typename F>
__device__ __forceinline__ float np_sum256(F p) {
  float half[2];
#pragma unroll
  for (int h = 0; h < 2; ++h) {
    const int base = h * 128;
    float s[16];
#pragma unroll
    for (int l = 0; l < 16; ++l) {
      float t01 = __fadd_rn(p(base + l),      p(base + 16 + l));
      float t23 = __fadd_rn(p(base + 32 + l), p(base + 48 + l));
      float t45 = __fadd_rn(p(base + 64 + l), p(base + 80 + l));
      float t67 = __fadd_rn(p(base + 96 + l), p(base + 112 + l));
      s[l] = __fadd_rn(__fadd_rn(t01, t23), __fadd_rn(t45, t67));
    }
#pragma unroll
    for (int w = 8; w >= 1; w >>= 1)
#pragma unroll
      for (int l = 0; l < w; ++l) s[l] = __fadd_rn(s[l], s[l + w]);
    half[h] = s[0];
  }
  return __fadd_rn(half[0], half[1]);
}

// np.einsum 'btd,kd->btk' optimize=False: baseline-compiled (SSE3, no FMA)
// sum_of_products_contig_contig_outstride0_two: per 16-elem chunk, lane l:
// v_l = p(d0) + (p(d0+4) + (p(d0+8) + (p(d0+12) + v_l))); final SSE3 hadd
// ((v0+v1)+(v2+v3)).
template <typename F>
__device__ __forceinline__ float np_einsum256(F p) {
  float v[4] = {0.f, 0.f, 0.f, 0.f};
#pragma unroll
  for (int c = 0; c < 16; ++c) {
#pragma unroll
    for (int l = 0; l < 4; ++l) {
      int d0 = c * 16 + l;
      float t = __fadd_rn(p(d0 + 12), v[l]);
      t = __fadd_rn(p(d0 + 8), t);
      t = __fadd_rn(p(d0 + 4), t);
      v[l] = __fadd_rn(p(d0), t);
    }
  }
  return __fadd_rn(__fadd_rn(v[0], v[1]), __fadd_rn(v[2], v[3]));
}

__global__ void rvq_zero(float* __restrict__ ws) { ws[0] = 0.f; }

// ---------------------------------------------------------------------------
// Precompute ||c_k||^2 for all Q*K codewords (coarse scoring only).
__global__ __launch_bounds__(256) void rvq_cnorm(const float* __restrict__ cb,
                                                 float* __restrict__ cn) {
  int k = blockIdx.x * 4 + (threadIdx.x >> 6);   // 0..4095
  int l = threadIdx.x & 63;
  const float* row = cb + (size_t)k * D_;
  float s = 0.f;
#pragma unroll
  for (int j = 0; j < 4; ++j) { float v = row[l + 64 * j]; s += v * v; }
#pragma unroll
  for (int off = 32; off; off >>= 1) s += __shfl_xor(s, off);
  if (l == 0) cn[k] = s;
}

// ---------------------------------------------------------------------------
// Fused RVQ. 32 tokens/block. LDS: residual 32x256 f32 (32K, swizzled) +
// codebook tile 64x64 f32 (16K, swizzled) + bestk[32]. ~48.4 KiB.
__global__ __launch_bounds__(256, 2) void rvq_main(const float* __restrict__ x,
                                                   const float* __restrict__ cb,
                                                   const float* __restrict__ cn,
                                                   float* __restrict__ out,
                                                   float* __restrict__ loss_ws) {
  __shared__ float4 rs4[TPB * 64];  // slot(t,c4) = t*64 + (c4 ^ ((t>>2)&3))
  __shared__ float4 cbt[64 * 16];   // slot(r,c)  = r*16 + (c ^ (r>>2))
  __shared__ int bestk[TPB];

  const int tid  = threadIdx.x;
  const int tok0 = blockIdx.x * TPB;

  const int ut = tid >> 3, uc = tid & 7;   // streaming: 8 threads per token
  const int ty = tid >> 4, tx = tid & 15;  // GEMM: 16x16 thread grid
  const int t0 = ty * 2;                   // 2 tokens per GEMM thread

  // ---- load x tile into residual LDS -------------------------------------
#pragma unroll
  for (int j = 0; j < 8; ++j) {
    int c4 = uc * 8 + j;
    float4 v = *(const float4*)&x[(size_t)(tok0 + ut) * D_ + c4 * 4];
    rs4[ut * 64 + (c4 ^ ((ut >> 2) & 3))] = v;
  }
  __syncthreads();

  float lsq = 0.f;

  for (int q = 0; q < Q_; ++q) {
    const float* cbq = cb + (size_t)q * K_ * D_;
    const float* cnq = cn + q * K_;

    // per-token top-2 (value, index), lexicographic (v,k)
    float v1[2], v2[2]; int k1[2], k2[2];
#pragma unroll
    for (int i = 0; i < 2; ++i) {
      v1[i] = v2[i] = 3.4e38f; k1[i] = k2[i] = 0x7FFFFFFF;
    }

    for (int nc = 0; nc < 16; ++nc) {          // codeword chunks of 64
      float acc[2][4];
#pragma unroll
      for (int i = 0; i < 2; ++i)
#pragma unroll
        for (int j = 0; j < 4; ++j) acc[i][j] = 0.f;

      for (int dc = 0; dc < 4; ++dc) {         // D chunks of 64
        __syncthreads();                       // cbt safe to overwrite
#pragma unroll
        for (int i = 0; i < 4; ++i) {
          int f = i * 256 + tid;
          int row = f >> 4, c = f & 15;
          float4 v = *(const float4*)&cbq[(size_t)(nc * 64 + row) * D_ + dc * 64 + c * 4];
          cbt[row * 16 + (c ^ (row >> 2))] = v;
        }
        __syncthreads();

#pragma unroll
        for (int d4 = 0; d4 < 16; ++d4) {
          float4 a[2], b[4];
#pragma unroll
          for (int i = 0; i < 2; ++i) {
            int t = t0 + i;
            int c4 = dc * 16 + d4;
            a[i] = rs4[t * 64 + (c4 ^ ((t >> 2) & 3))];
          }
#pragma unroll
          for (int j = 0; j < 4; ++j) {
            int row = tx * 4 + j;
            b[j] = cbt[row * 16 + (d4 ^ tx)];
          }
#pragma unroll
          for (int i = 0; i < 2; ++i)
#pragma unroll
            for (int j = 0; j < 4; ++j)
              acc[i][j] += a[i].x * b[j].x + a[i].y * b[j].y +
                           a[i].z * b[j].z + a[i].w * b[j].w;
        }
      }

      // score = ||c||^2 - 2 r.c ; per-lane top-2 (tie -> lowest k)
#pragma unroll
      for (int j = 0; j < 4; ++j) {
        int k = nc * 64 + tx * 4 + j;
        float c2 = cnq[k];
#pragma unroll
        for (int i = 0; i < 2; ++i) {
          float s = c2 - 2.f * acc[i][j];
          if (lt2(s, k, v1[i], k1[i])) {
            v2[i] = v1[i]; k2[i] = k1[i]; v1[i] = s; k1[i] = k;
          } else if (lt2(s, k, v2[i], k2[i])) {
            v2[i] = s; k2[i] = k;
          }
        }
      }
    }

    // ---- cross-lane top-2 merge over the 16 tx lanes ----------------------
#pragma unroll
    for (int i = 0; i < 2; ++i) {
      float a1 = v1[i]; int b1 = k1[i];
      float a2 = v2[i]; int b2 = k2[i];
#pragma unroll
      for (int off = 1; off < 16; off <<= 1) {
        float o1 = __shfl_xor(a1, off); int p1 = __shfl_xor(b1, off);
        float o2 = __shfl_xor(a2, off); int p2 = __shfl_xor(b2, off);
        if (lt2(o1, p1, a1, b1)) {
          if (lt2(a1, b1, o2, p2)) { a2 = a1; b2 = b1; }
          else                     { a2 = o2; b2 = p2; }
          a1 = o1; b1 = p1;
        } else if (lt2(o1, p1, a2, b2)) {
          a2 = o1; b2 = p1;
        }
      }
      if (tx == 0) {
        int t = t0 + i;
        int kk = b1 & (K_ - 1);
        if (a2 - a1 < MARGIN) {
          // Near-tie: adjudicate by bit-exact numpy-fp32 emulation of
          //   d = fl( fl(A - fl(2*E)) + C )
          // A = np.sum(r*r,-1)  [AVX512 pairwise path],
          // E = np.einsum       [baseline SSE3 chained, no FMA],
          // C = np.sum(c*c,-1)  [AVX512 pairwise path].
          // First-occurrence (lowest k) on exact fp32 tie = np.argmin.
          int kb = b2 & (K_ - 1);
          const float* rowA = cbq + (size_t)kk * D_;
          const float* rowB = cbq + (size_t)kb * D_;
          const float* rsf = (const float*)rs4;
          const int tt = t;
          auto rd = [&](int d) -> float {
            return rsf[(tt * 64 + ((d >> 2) ^ ((tt >> 2) & 3))) * 4 + (d & 3)];
          };
          float A  = np_sum256([&](int d) { float r = rd(d); return __fmul_rn(r, r); });
          float Ea = np_einsum256([&](int d) { return __fmul_rn(rd(d), rowA[d]); });
          float Ca = np_sum256([&](int d) { float c = rowA[d]; return __fmul_rn(c, c); });
          float Eb = np_einsum256([&](int d) { return __fmul_rn(rd(d), rowB[d]); });
          float Cb = np_sum256([&](int d) { float c = rowB[d]; return __fmul_rn(c, c); });
          float da = __fadd_rn(__fsub_rn(A, __fmul_rn(2.f, Ea)), Ca);
          float db = __fadd_rn(__fsub_rn(A, __fmul_rn(2.f, Eb)), Cb);
          if (db < da || (db == da && kb < kk)) kk = kb;
        }
        bestk[t] = kk;
        out[QUANT_N + q * NTOK + tok0 + t] = (float)kk;   // exact f32 integer
      }
    }
    __syncthreads();           // bestk visible; all GEMM/rescore rs4 reads done

    // ---- residual update + loss partial ----------------------------------
    {
      int kk = bestk[ut] & (K_ - 1);
      const float* crow = cbq + (size_t)kk * D_;
#pragma unroll
      for (int j = 0; j < 8; ++j) {
        int c4 = uc * 8 + j;
        float4 cv = *(const float4*)&crow[c4 * 4];
        int slot = ut * 64 + (c4 ^ ((ut >> 2) & 3));
        float4 rv = rs4[slot];
        rv.x -= cv.x; rv.y -= cv.y; rv.z -= cv.z; rv.w -= cv.w;
        rs4[slot] = rv;
        lsq += rv.x * rv.x + rv.y * rv.y + rv.z * rv.z + rv.w * rv.w;
      }
    }
    // next stage's first __syncthreads (dc loop) orders rs4/bestk reuse
  }
  __syncthreads();

  // ---- quant = x - r_final, write f32 ------------------------------------
#pragma unroll
  for (int j = 0; j < 8; ++j) {
    int c4 = uc * 8 + j;
    float4 xv = *(const float4*)&x[(size_t)(tok0 + ut) * D_ + c4 * 4];
    float4 rv = rs4[ut * 64 + (c4 ^ ((ut >> 2) & 3))];
    float4 o;
    o.x = xv.x - rv.x; o.y = xv.y - rv.y;
    o.z = xv.z - rv.z; o.w = xv.w - rv.w;
    *(float4*)&out[(size_t)(tok0 + ut) * D_ + c4 * 4] = o;
  }

  // ---- loss: wave reduce + one atomic per wave ---------------------------
#pragma unroll
  for (int off = 32; off; off >>= 1) lsq += __shfl_xor(lsq, off);
  if ((tid & 63) == 0) atomicAdd(loss_ws, lsq);
}

// ---------------------------------------------------------------------------
__global__ void rvq_finalize(const float* __restrict__ ws,
                             float* __restrict__ out) {
  if (threadIdx.x == 0) {
    float loss = 1.25f * ws[0] * (1.0f / (float)QUANT_N);
#pragma unroll
    for (int i = 0; i < 4; ++i) out[LOSS_OFF + i] = loss;
  }
}

// ---------------------------------------------------------------------------
extern "C" void kernel_launch(void* const* d_in, const int* in_sizes, int n_in,
                              void* d_out, int out_size, void* d_ws, size_t ws_size,
                              hipStream_t stream) {
  // Identify x (8388608 elems) vs codebooks (1048576) by size, order-robust.
  const float* x  = (const float*)d_in[0];
  const float* cb = (const float*)d_in[1];
  if (n_in >= 2 && in_sizes[0] != QUANT_N) {
    x  = (const float*)d_in[1];
    cb = (const float*)d_in[0];
  }
  float* out = (float*)d_out;

  float* ws = (float*)d_ws;
  float* cn = ws + 64;                       // 4096 floats of ||c||^2

  rvq_zero<<<1, 1, 0, stream>>>(ws);         // zero loss accumulator (capture-safe)
  rvq_cnorm<<<K_ * Q_ / 4, 256, 0, stream>>>(cb, cn);
  rvq_main<<<NTOK / TPB, 256, 0, stream>>>(x, cb, cn, out, ws);
  rvq_finalize<<<1, 64, 0, stream>>>(ws, out);
}

// Round 9
// 705.090 us; speedup vs baseline: 2.7313x; 2.7313x over previous
//
#include <hip/hip_runtime.h>

// RVQTokenizer: x[16,2048,256] f32, codebooks[4,1024,256] f32.
// Outputs (flat f32): quant[16,2048,256], indices[4,16,2048] (as float),
// 4 scalar losses (all = total vq_loss).
#define B_    16
#define T_    2048
#define D_    256
#define Q_    4
#define K_    1024
#define NTOK  (B_ * T_)            // 32768
#define QUANT_N (NTOK * D_)        // 8388608
#define IDX_N   (Q_ * NTOK)        // 131072
#define LOSS_OFF (QUANT_N + IDX_N) // 8519680
#define MARGIN_MFMA 0.06f          // fp16-coarse ambiguity window
#define MARGIN_V8   0.03f          // fp32-coarse window (fallback kernel)

typedef __attribute__((ext_vector_type(8))) _Float16 f16x8;
typedef __attribute__((ext_vector_type(4))) _Float16 f16x4;
typedef __attribute__((ext_vector_type(4))) float    f32x4;

__device__ __forceinline__ bool lt2(float v, int k, float w, int m) {
  return v < w || (v == w && k < m);
}

// ---------------------------------------------------------------------------
// Bit-exact numpy emulation (verified PASS in round 8).
// np.sum over 256 contiguous: pairwise split into two 128-halves; each half =
// AVX512F 16-lane path (8 accumulators in one pass, vector tree, reduce fold).
template <typename F>
__device__ __forceinline__ float np_sum256(F p) {
  float half[2];
#pragma unroll
  for (int h = 0; h < 2; ++h) {
    const int base = h * 128;
    float s[16];
#pragma unroll
    for (int l = 0; l < 16; ++l) {
      float t01 = __fadd_rn(p(base + l),      p(base + 16 + l));
      float t23 = __fadd_rn(p(base + 32 + l), p(base + 48 + l));
      float t45 = __fadd_rn(p(base + 64 + l), p(base + 80 + l));
      float t67 = __fadd_rn(p(base + 96 + l), p(base + 112 + l));
      s[l] = __fadd_rn(__fadd_rn(t01, t23), __fadd_rn(t45, t67));
    }
#pragma unroll
    for (int w = 8; w >= 1; w >>= 1)
#pragma unroll
      for (int l = 0; l < w; ++l) s[l] = __fadd_rn(s[l], s[l + w]);
    half[h] = s[0];
  }
  return __fadd_rn(half[0], half[1]);
}

// np.einsum (optimize=False, baseline SSE3, no FMA): chained per 16-elem chunk.
template <typename F>
__device__ __forceinline__ float np_einsum256(F p) {
  float v[4] = {0.f, 0.f, 0.f, 0.f};
#pragma unroll
  for (int c = 0; c < 16; ++c) {
#pragma unroll
    for (int l = 0; l < 4; ++l) {
      int d0 = c * 16 + l;
      float t = __fadd_rn(p(d0 + 12), v[l]);
      t = __fadd_rn(p(d0 + 8), t);
      t = __fadd_rn(p(d0 + 4), t);
      v[l] = __fadd_rn(p(d0), t);
    }
  }
  return __fadd_rn(__fadd_rn(v[0], v[1]), __fadd_rn(v[2], v[3]));
}

__global__ void rvq_zero(float* __restrict__ ws) { ws[0] = 0.f; }

// ---------------------------------------------------------------------------
// Prep: cn[k]=||c_k||^2 (coarse only) and fp16 codebook copy.
__global__ __launch_bounds__(256) void rvq_prep(const float* __restrict__ cb,
                                                float* __restrict__ cn,
                                                _Float16* __restrict__ cbh) {
  int k = blockIdx.x * 4 + (threadIdx.x >> 6);   // 0..4095
  int l = threadIdx.x & 63;
  const float* row = cb + (size_t)k * D_;
  float s = 0.f;
#pragma unroll
  for (int j = 0; j < 4; ++j) { float v = row[l + 64 * j]; s += v * v; }
#pragma unroll
  for (int off = 32; off; off >>= 1) s += __shfl_xor(s, off);
  if (l == 0) cn[k] = s;
  // fp16 conversion, coalesced float4 per thread
  int gid = blockIdx.x * 256 + threadIdx.x;      // 0..262143
  float4 v = *(const float4*)&cb[(size_t)gid * 4];
  f16x4 h;
  h[0] = (_Float16)v.x; h[1] = (_Float16)v.y;
  h[2] = (_Float16)v.z; h[3] = (_Float16)v.w;
  *(f16x4*)&cbh[(size_t)gid * 4] = h;
}

__device__ __forceinline__ void ins3(float* tv, int* tk, float v, int k) {
  if (lt2(v, k, tv[0], tk[0])) {
    tv[2] = tv[1]; tk[2] = tk[1]; tv[1] = tv[0]; tk[1] = tk[0];
    tv[0] = v; tk[0] = k;
  } else if (lt2(v, k, tv[1], tk[1])) {
    tv[2] = tv[1]; tk[2] = tk[1]; tv[1] = v; tk[1] = k;
  } else if (lt2(v, k, tv[2], tk[2])) {
    tv[2] = v; tk[2] = k;
  }
}

// ---------------------------------------------------------------------------
// MFMA RVQ. 64 tokens/block, 256 threads (4 waves, 1 M-tile each).
// rs (residual) linear fp32 in LDS; A-frags fp16 hi/lo in registers per stage;
// B-frags per-lane 16B global loads from L2-resident fp16 codebook.
__global__ __launch_bounds__(256, 2) void rvq_mfma(const float* __restrict__ x,
                                                   const float* __restrict__ cb,
                                                   const float* __restrict__ cn,
                                                   const _Float16* __restrict__ cbh,
                                                   float* __restrict__ out,
                                                   float* __restrict__ loss_ws) {
  __shared__ float rs[64 * 256];   // 64 KiB, linear [t][d]
  __shared__ int bestk[64];

  const int tid  = threadIdx.x;
  const int tok0 = blockIdx.x * 64;
  const int lane = tid & 63;
  const int wv   = tid >> 6;       // wave id = M-tile (tokens wv*16..+15)
  const int l15  = lane & 15;      // A-row / B-col / D-col index
  const int lg   = lane >> 4;      // k-group / D-row-group
  const int ut   = tid >> 2, uc = tid & 3;   // streaming: 4 threads per token

  // ---- load x -> rs -------------------------------------------------------
#pragma unroll
  for (int j = 0; j < 16; ++j) {
    int c4 = j * 4 + uc;
    *(float4*)&rs[ut * 256 + c4 * 4] =
        *(const float4*)&x[(size_t)(tok0 + ut) * D_ + c4 * 4];
  }
  __syncthreads();

  float lsq = 0.f;

  for (int q = 0; q < Q_; ++q) {
    const float*    cbq  = cb  + (size_t)q * K_ * D_;
    const float*    cnq  = cn  + q * K_;
    const _Float16* cbhq = cbh + (size_t)q * K_ * D_;

    // ---- A fragments (fp16 hi/lo) for this wave's 16 token rows ----------
    f16x8 Ah[8], Al[8];
    {
      const float* rrow = &rs[(wv * 16 + l15) * 256];
#pragma unroll
      for (int ks = 0; ks < 8; ++ks) {
        float4 v0 = *(const float4*)&rrow[ks * 32 + lg * 8];
        float4 v1 = *(const float4*)&rrow[ks * 32 + lg * 8 + 4];
        float vv[8] = {v0.x, v0.y, v0.z, v0.w, v1.x, v1.y, v1.z, v1.w};
        f16x8 h, l;
#pragma unroll
        for (int j = 0; j < 8; ++j) {
          _Float16 hj = (_Float16)vv[j];
          h[j] = hj;
          l[j] = (_Float16)(vv[j] - (float)hj);
        }
        Ah[ks] = h; Al[ks] = l;
      }
    }

    // ---- top-3 state: tokens m = wv*16 + lg*4 + r -------------------------
    float tv[4][3]; int tk[4][3];
#pragma unroll
    for (int r = 0; r < 4; ++r)
#pragma unroll
      for (int i = 0; i < 3; ++i) { tv[r][i] = 3.4e38f; tk[r][i] = 0x7FFFFFFF; }

    for (int Nt = 0; Nt < 64; ++Nt) {
      const int n = Nt * 16 + l15;                       // codeword index
      const _Float16* brow = cbhq + (size_t)n * D_;
      f32x4 accH = {0.f, 0.f, 0.f, 0.f}, accL = {0.f, 0.f, 0.f, 0.f};
#pragma unroll
      for (int ks = 0; ks < 8; ++ks) {
        f16x8 b = *(const f16x8*)&brow[ks * 32 + lg * 8];
        accH = __builtin_amdgcn_mfma_f32_16x16x32_f16(Ah[ks], b, accH, 0, 0, 0);
        accL = __builtin_amdgcn_mfma_f32_16x16x32_f16(Al[ks], b, accL, 0, 0, 0);
      }
      float c2 = cnq[n];
#pragma unroll
      for (int r = 0; r < 4; ++r) {
        float s = c2 - 2.f * (accH[r] + accL[r]);
        ins3(tv[r], tk[r], s, n);
      }
    }

    // ---- merge top-3 across the 16 l15 lanes ------------------------------
#pragma unroll
    for (int r = 0; r < 4; ++r) {
#pragma unroll
      for (int off = 1; off < 16; off <<= 1) {
        float ov[3]; int ok[3];
#pragma unroll
        for (int i = 0; i < 3; ++i) {
          ov[i] = __shfl_xor(tv[r][i], off);
          ok[i] = __shfl_xor(tk[r][i], off);
        }
#pragma unroll
        for (int i = 0; i < 3; ++i) ins3(tv[r], tk[r], ov[i], ok[i]);
      }
    }

    // ---- leaders adjudicate + write indices -------------------------------
    if (l15 == 0) {
#pragma unroll
      for (int r = 0; r < 4; ++r) {
        int t = wv * 16 + lg * 4 + r;     // local token
        int kk = tk[r][0] & (K_ - 1);
        if (tv[r][1] - tv[r][0] < MARGIN_MFMA) {
          // np-exact rescore among coarse top candidates
          const float* rsrow = &rs[t * 256];
          float A = np_sum256([&](int d) {
            float rr = rsrow[d]; return __fmul_rn(rr, rr);
          });
          int cand[3]; int ncand = 1;
          cand[0] = kk;
          cand[ncand++] = tk[r][1] & (K_ - 1);
          if (tv[r][2] - tv[r][0] < MARGIN_MFMA) cand[ncand++] = tk[r][2] & (K_ - 1);
          float bd = 3.4e38f; int bk2 = 0x7FFFFFFF;
          for (int i = 0; i < ncand; ++i) {
            const float* crow = cbq + (size_t)cand[i] * D_;
            float E = np_einsum256([&](int d) {
              return __fmul_rn(rsrow[d], crow[d]);
            });
            float C = np_sum256([&](int d) {
              float cc = crow[d]; return __fmul_rn(cc, cc);
            });
            float dd = __fadd_rn(__fsub_rn(A, __fmul_rn(2.f, E)), C);
            if (dd < bd || (dd == bd && cand[i] < bk2)) { bd = dd; bk2 = cand[i]; }
          }
          kk = bk2;
        }
        bestk[t] = kk;
        out[QUANT_N + q * NTOK + tok0 + t] = (float)kk;
      }
    }
    __syncthreads();          // bestk visible; rs reads (A/adjudicate) done

    // ---- residual update + loss -------------------------------------------
    {
      int kk = bestk[ut] & (K_ - 1);
      const float* crow = cbq + (size_t)kk * D_;
#pragma unroll
      for (int j = 0; j < 16; ++j) {
        int c4 = j * 4 + uc;
        float4 cv = *(const float4*)&crow[c4 * 4];
        float4 rv = *(float4*)&rs[ut * 256 + c4 * 4];
        rv.x -= cv.x; rv.y -= cv.y; rv.z -= cv.z; rv.w -= cv.w;
        *(float4*)&rs[ut * 256 + c4 * 4] = rv;
        lsq += rv.x * rv.x + rv.y * rv.y + rv.z * rv.z + rv.w * rv.w;
      }
    }
    __syncthreads();          // rs updated before next stage's A-read
  }

  // ---- quant = x - r_final -------------------------------------------------
#pragma unroll
  for (int j = 0; j < 16; ++j) {
    int c4 = j * 4 + uc;
    float4 xv = *(const float4*)&x[(size_t)(tok0 + ut) * D_ + c4 * 4];
    float4 rv = *(const float4*)&rs[ut * 256 + c4 * 4];
    float4 o;
    o.x = xv.x - rv.x; o.y = xv.y - rv.y;
    o.z = xv.z - rv.z; o.w = xv.w - rv.w;
    *(float4*)&out[(size_t)(tok0 + ut) * D_ + c4 * 4] = o;
  }

  // ---- loss: wave reduce + one atomic per wave -----------------------------
#pragma unroll
  for (int off = 32; off; off >>= 1) lsq += __shfl_xor(lsq, off);
  if ((tid & 63) == 0) atomicAdd(loss_ws, lsq);
}

// ---------------------------------------------------------------------------
// FALLBACK (round-8 kernel, verbatim): used only if ws is too small for cbh.
__global__ __launch_bounds__(256) void rvq_cnorm(const float* __restrict__ cb,
                                                 float* __restrict__ cn) {
  int k = blockIdx.x * 4 + (threadIdx.x >> 6);
  int l = threadIdx.x & 63;
  const float* row = cb + (size_t)k * D_;
  float s = 0.f;
#pragma unroll
  for (int j = 0; j < 4; ++j) { float v = row[l + 64 * j]; s += v * v; }
#pragma unroll
  for (int off = 32; off; off >>= 1) s += __shfl_xor(s, off);
  if (l == 0) cn[k] = s;
}

__global__ __launch_bounds__(256, 2) void rvq_main_v8(const float* __restrict__ x,
                                                      const float* __restrict__ cb,
                                                      const float* __restrict__ cn,
                                                      float* __restrict__ out,
                                                      float* __restrict__ loss_ws) {
  __shared__ float4 rs4[32 * 64];
  __shared__ float4 cbt[64 * 16];
  __shared__ int bestk[32];
  const int tid  = threadIdx.x;
  const int tok0 = blockIdx.x * 32;
  const int ut = tid >> 3, uc = tid & 7;
  const int ty = tid >> 4, tx = tid & 15;
  const int t0 = ty * 2;
#pragma unroll
  for (int j = 0; j < 8; ++j) {
    int c4 = uc * 8 + j;
    float4 v = *(const float4*)&x[(size_t)(tok0 + ut) * D_ + c4 * 4];
    rs4[ut * 64 + (c4 ^ ((ut >> 2) & 3))] = v;
  }
  __syncthreads();
  float lsq = 0.f;
  for (int q = 0; q < Q_; ++q) {
    const float* cbq = cb + (size_t)q * K_ * D_;
    const float* cnq = cn + q * K_;
    float v1[2], v2[2]; int k1[2], k2[2];
#pragma unroll
    for (int i = 0; i < 2; ++i) { v1[i] = v2[i] = 3.4e38f; k1[i] = k2[i] = 0x7FFFFFFF; }
    for (int nc = 0; nc < 16; ++nc) {
      float acc[2][4];
#pragma unroll
      for (int i = 0; i < 2; ++i)
#pragma unroll
        for (int j = 0; j < 4; ++j) acc[i][j] = 0.f;
      for (int dc = 0; dc < 4; ++dc) {
        __syncthreads();
#pragma unroll
        for (int i = 0; i < 4; ++i) {
          int f = i * 256 + tid;
          int row = f >> 4, c = f & 15;
          float4 v = *(const float4*)&cbq[(size_t)(nc * 64 + row) * D_ + dc * 64 + c * 4];
          cbt[row * 16 + (c ^ (row >> 2))] = v;
        }
        __syncthreads();
#pragma unroll
        for (int d4 = 0; d4 < 16; ++d4) {
          float4 a[2], b[4];
#pragma unroll
          for (int i = 0; i < 2; ++i) {
            int t = t0 + i;
            int c4 = dc * 16 + d4;
            a[i] = rs4[t * 64 + (c4 ^ ((t >> 2) & 3))];
          }
#pragma unroll
          for (int j = 0; j < 4; ++j) {
            int row = tx * 4 + j;
            b[j] = cbt[row * 16 + (d4 ^ tx)];
          }
#pragma unroll
          for (int i = 0; i < 2; ++i)
#pragma unroll
            for (int j = 0; j < 4; ++j)
              acc[i][j] += a[i].x * b[j].x + a[i].y * b[j].y +
                           a[i].z * b[j].z + a[i].w * b[j].w;
        }
      }
#pragma unroll
      for (int j = 0; j < 4; ++j) {
        int k = nc * 64 + tx * 4 + j;
        float c2 = cnq[k];
#pragma unroll
        for (int i = 0; i < 2; ++i) {
          float s = c2 - 2.f * acc[i][j];
          if (lt2(s, k, v1[i], k1[i])) { v2[i] = v1[i]; k2[i] = k1[i]; v1[i] = s; k1[i] = k; }
          else if (lt2(s, k, v2[i], k2[i])) { v2[i] = s; k2[i] = k; }
        }
      }
    }
#pragma unroll
    for (int i = 0; i < 2; ++i) {
      float a1 = v1[i]; int b1 = k1[i];
      float a2 = v2[i]; int b2 = k2[i];
#pragma unroll
      for (int off = 1; off < 16; off <<= 1) {
        float o1 = __shfl_xor(a1, off); int p1 = __shfl_xor(b1, off);
        float o2 = __shfl_xor(a2, off); int p2 = __shfl_xor(b2, off);
        if (lt2(o1, p1, a1, b1)) {
          if (lt2(a1, b1, o2, p2)) { a2 = a1; b2 = b1; } else { a2 = o2; b2 = p2; }
          a1 = o1; b1 = p1;
        } else if (lt2(o1, p1, a2, b2)) { a2 = o1; b2 = p1; }
      }
      if (tx == 0) {
        int t = t0 + i;
        int kk = b1 & (K_ - 1);
        if (a2 - a1 < MARGIN_V8) {
          int kb = b2 & (K_ - 1);
          const float* rowA = cbq + (size_t)kk * D_;
          const float* rowB = cbq + (size_t)kb * D_;
          const float* rsf = (const float*)rs4;
          const int tt = t;
          auto rd = [&](int d) -> float {
            return rsf[(tt * 64 + ((d >> 2) ^ ((tt >> 2) & 3))) * 4 + (d & 3)];
          };
          float A  = np_sum256([&](int d) { float r = rd(d); return __fmul_rn(r, r); });
          float Ea = np_einsum256([&](int d) { return __fmul_rn(rd(d), rowA[d]); });
          float Ca = np_sum256([&](int d) { float c = rowA[d]; return __fmul_rn(c, c); });
          float Eb = np_einsum256([&](int d) { return __fmul_rn(rd(d), rowB[d]); });
          float Cb = np_sum256([&](int d) { float c = rowB[d]; return __fmul_rn(c, c); });
          float da = __fadd_rn(__fsub_rn(A, __fmul_rn(2.f, Ea)), Ca);
          float db = __fadd_rn(__fsub_rn(A, __fmul_rn(2.f, Eb)), Cb);
          if (db < da || (db == da && kb < kk)) kk = kb;
        }
        bestk[t] = kk;
        out[QUANT_N + q * NTOK + tok0 + t] = (float)kk;
      }
    }
    __syncthreads();
    {
      int kk = bestk[ut] & (K_ - 1);
      const float* crow = cbq + (size_t)kk * D_;
#pragma unroll
      for (int j = 0; j < 8; ++j) {
        int c4 = uc * 8 + j;
        float4 cv = *(const float4*)&crow[c4 * 4];
        int slot = ut * 64 + (c4 ^ ((ut >> 2) & 3));
        float4 rv = rs4[slot];
        rv.x -= cv.x; rv.y -= cv.y; rv.z -= cv.z; rv.w -= cv.w;
        rs4[slot] = rv;
        lsq += rv.x * rv.x + rv.y * rv.y + rv.z * rv.z + rv.w * rv.w;
      }
    }
  }
  __syncthreads();
#pragma unroll
  for (int j = 0; j < 8; ++j) {
    int c4 = uc * 8 + j;
    float4 xv = *(const float4*)&x[(size_t)(tok0 + ut) * D_ + c4 * 4];
    float4 rv = rs4[ut * 64 + (c4 ^ ((ut >> 2) & 3))];
    float4 o;
    o.x = xv.x - rv.x; o.y = xv.y - rv.y;
    o.z = xv.z - rv.z; o.w = xv.w - rv.w;
    *(float4*)&out[(size_t)(tok0 + ut) * D_ + c4 * 4] = o;
  }
#pragma unroll
  for (int off = 32; off; off >>= 1) lsq += __shfl_xor(lsq, off);
  if ((tid & 63) == 0) atomicAdd(loss_ws, lsq);
}

// ---------------------------------------------------------------------------
__global__ void rvq_finalize(const float* __restrict__ ws,
                             float* __restrict__ out) {
  if (threadIdx.x == 0) {
    float loss = 1.25f * ws[0] * (1.0f / (float)QUANT_N);
#pragma unroll
    for (int i = 0; i < 4; ++i) out[LOSS_OFF + i] = loss;
  }
}

// ---------------------------------------------------------------------------
extern "C" void kernel_launch(void* const* d_in, const int* in_sizes, int n_in,
                              void* d_out, int out_size, void* d_ws, size_t ws_size,
                              hipStream_t stream) {
  const float* x  = (const float*)d_in[0];
  const float* cb = (const float*)d_in[1];
  if (n_in >= 2 && in_sizes[0] != QUANT_N) {
    x  = (const float*)d_in[1];
    cb = (const float*)d_in[0];
  }
  float* out = (float*)d_out;

  float* ws = (float*)d_ws;
  float* cn = ws + 64;                                  // 4096 f32
  _Float16* cbh = (_Float16*)(ws + 64 + Q_ * K_);       // 2 MB fp16 codebook
  size_t need = (size_t)(64 + Q_ * K_) * 4 + (size_t)Q_ * K_ * D_ * 2 + 256;

  rvq_zero<<<1, 1, 0, stream>>>(ws);
  if (ws_size >= need) {
    rvq_prep<<<Q_ * K_ / 4, 256, 0, stream>>>(cb, cn, cbh);
    rvq_mfma<<<NTOK / 64, 256, 0, stream>>>(x, cb, cn, cbh, out, ws);
  } else {
    rvq_cnorm<<<Q_ * K_ / 4, 256, 0, stream>>>(cb, cn);
    rvq_main_v8<<<NTOK / 32, 256, 0, stream>>>(x, cb, cn, out, ws);
  }
  rvq_finalize<<<1, 64, 0, stream>>>(ws, out);
}

// Round 10
// 620.900 us; speedup vs baseline: 3.1017x; 1.1356x over previous
//
#include <hip/hip_runtime.h>

// RVQTokenizer: x[16,2048,256] f32, codebooks[4,1024,256] f32.
// Outputs (flat f32): quant[16,2048,256], indices[4,16,2048] (as float),
// 4 scalar losses (all = total vq_loss).
#define B_    16
#define T_    2048
#define D_    256
#define Q_    4
#define K_    1024
#define NTOK  (B_ * T_)            // 32768
#define QUANT_N (NTOK * D_)        // 8388608
#define IDX_N   (Q_ * NTOK)        // 131072
#define LOSS_OFF (QUANT_N + IDX_N) // 8519680
#define MARGIN_MFMA 0.06f          // fp16-coarse ambiguity window
#define MARGIN_V8   0.03f          // fp32-coarse window (fallback kernel)

typedef __attribute__((ext_vector_type(8))) _Float16 f16x8;
typedef __attribute__((ext_vector_type(4))) _Float16 f16x4;
typedef __attribute__((ext_vector_type(4))) float    f32x4;

__device__ __forceinline__ bool lt2(float v, int k, float w, int m) {
  return v < w || (v == w && k < m);
}

// ---------------------------------------------------------------------------
// Bit-exact numpy emulation (verified PASS in rounds 8/9).
template <typename F>
__device__ __forceinline__ float np_sum256(F p) {
  float half[2];
#pragma unroll
  for (int h = 0; h < 2; ++h) {
    const int base = h * 128;
    float s[16];
#pragma unroll
    for (int l = 0; l < 16; ++l) {
      float t01 = __fadd_rn(p(base + l),      p(base + 16 + l));
      float t23 = __fadd_rn(p(base + 32 + l), p(base + 48 + l));
      float t45 = __fadd_rn(p(base + 64 + l), p(base + 80 + l));
      float t67 = __fadd_rn(p(base + 96 + l), p(base + 112 + l));
      s[l] = __fadd_rn(__fadd_rn(t01, t23), __fadd_rn(t45, t67));
    }
#pragma unroll
    for (int w = 8; w >= 1; w >>= 1)
#pragma unroll
      for (int l = 0; l < w; ++l) s[l] = __fadd_rn(s[l], s[l + w]);
    half[h] = s[0];
  }
  return __fadd_rn(half[0], half[1]);
}

template <typename F>
__device__ __forceinline__ float np_einsum256(F p) {
  float v[4] = {0.f, 0.f, 0.f, 0.f};
#pragma unroll
  for (int c = 0; c < 16; ++c) {
#pragma unroll
    for (int l = 0; l < 4; ++l) {
      int d0 = c * 16 + l;
      float t = __fadd_rn(p(d0 + 12), v[l]);
      t = __fadd_rn(p(d0 + 8), t);
      t = __fadd_rn(p(d0 + 4), t);
      v[l] = __fadd_rn(p(d0), t);
    }
  }
  return __fadd_rn(__fadd_rn(v[0], v[1]), __fadd_rn(v[2], v[3]));
}

__global__ void rvq_zero(float* __restrict__ ws) { ws[0] = 0.f; }

// ---------------------------------------------------------------------------
// Prep: cn[k]=||c_k||^2 (coarse only) and fp16 codebook copy.
__global__ __launch_bounds__(256) void rvq_prep(const float* __restrict__ cb,
                                                float* __restrict__ cn,
                                                _Float16* __restrict__ cbh) {
  int k = blockIdx.x * 4 + (threadIdx.x >> 6);   // 0..4095
  int l = threadIdx.x & 63;
  const float* row = cb + (size_t)k * D_;
  float s = 0.f;
#pragma unroll
  for (int j = 0; j < 4; ++j) { float v = row[l + 64 * j]; s += v * v; }
#pragma unroll
  for (int off = 32; off; off >>= 1) s += __shfl_xor(s, off);
  if (l == 0) cn[k] = s;
  int gid = blockIdx.x * 256 + threadIdx.x;      // 0..262143
  float4 v = *(const float4*)&cb[(size_t)gid * 4];
  f16x4 h;
  h[0] = (_Float16)v.x; h[1] = (_Float16)v.y;
  h[2] = (_Float16)v.z; h[3] = (_Float16)v.w;
  *(f16x4*)&cbh[(size_t)gid * 4] = h;
}

__device__ __forceinline__ void ins3(float* tv, int* tk, float v, int k) {
  if (lt2(v, k, tv[0], tk[0])) {
    tv[2] = tv[1]; tk[2] = tk[1]; tv[1] = tv[0]; tk[1] = tk[0];
    tv[0] = v; tk[0] = k;
  } else if (lt2(v, k, tv[1], tk[1])) {
    tv[2] = tv[1]; tk[2] = tk[1]; tv[1] = v; tk[1] = k;
  } else if (lt2(v, k, tv[2], tk[2])) {
    tv[2] = v; tk[2] = k;
  }
}

// load B fragments for codeword group Nt (8 x f16x8 per lane)
__device__ __forceinline__ void ldB(const _Float16* __restrict__ cbhq,
                                    int Nt, int l15, int lg, f16x8* bb) {
  const _Float16* brow = cbhq + (size_t)(Nt * 16 + l15) * D_ + lg * 8;
#pragma unroll
  for (int ks = 0; ks < 8; ++ks) bb[ks] = *(const f16x8*)&brow[ks * 32];
}

// ---------------------------------------------------------------------------
// MFMA RVQ. 64 tokens/block, 256 threads (4 waves, 1 M-tile each).
// B-panel loads are software-pipelined one Nt ahead (b0/b1 double buffer).
__global__ __launch_bounds__(256, 2) void rvq_mfma(const float* __restrict__ x,
                                                   const float* __restrict__ cb,
                                                   const float* __restrict__ cn,
                                                   const _Float16* __restrict__ cbh,
                                                   float* __restrict__ out,
                                                   float* __restrict__ loss_ws) {
  __shared__ float rs[64 * 256];   // 64 KiB, linear [t][d]
  __shared__ int bestk[64];

  const int tid  = threadIdx.x;
  const int tok0 = blockIdx.x * 64;
  const int lane = tid & 63;
  const int wv   = tid >> 6;       // wave id = M-tile (tokens wv*16..+15)
  const int l15  = lane & 15;      // A-row / B-col / D-col index
  const int lg   = lane >> 4;      // k-group / D-row-group
  const int ut   = tid >> 2, uc = tid & 3;   // streaming: 4 threads per token

  // ---- load x -> rs -------------------------------------------------------
#pragma unroll
  for (int j = 0; j < 16; ++j) {
    int c4 = j * 4 + uc;
    *(float4*)&rs[ut * 256 + c4 * 4] =
        *(const float4*)&x[(size_t)(tok0 + ut) * D_ + c4 * 4];
  }
  __syncthreads();

  float lsq = 0.f;

  for (int q = 0; q < Q_; ++q) {
    const float*    cbq  = cb  + (size_t)q * K_ * D_;
    const float*    cnq  = cn  + q * K_;
    const _Float16* cbhq = cbh + (size_t)q * K_ * D_;

    // ---- A fragments (fp16 hi/lo) for this wave's 16 token rows ----------
    f16x8 Ah[8], Al[8];
    {
      const float* rrow = &rs[(wv * 16 + l15) * 256];
#pragma unroll
      for (int ks = 0; ks < 8; ++ks) {
        float4 v0 = *(const float4*)&rrow[ks * 32 + lg * 8];
        float4 v1 = *(const float4*)&rrow[ks * 32 + lg * 8 + 4];
        float vv[8] = {v0.x, v0.y, v0.z, v0.w, v1.x, v1.y, v1.z, v1.w};
        f16x8 h, l;
#pragma unroll
        for (int j = 0; j < 8; ++j) {
          _Float16 hj = (_Float16)vv[j];
          h[j] = hj;
          l[j] = (_Float16)(vv[j] - (float)hj);
        }
        Ah[ks] = h; Al[ks] = l;
      }
    }

    // ---- top-3 state: tokens m = wv*16 + lg*4 + r -------------------------
    float tv[4][3]; int tk[4][3];
#pragma unroll
    for (int r = 0; r < 4; ++r)
#pragma unroll
      for (int i = 0; i < 3; ++i) { tv[r][i] = 3.4e38f; tk[r][i] = 0x7FFFFFFF; }

    // ---- coarse scoring, 1-deep software pipeline (b0/b1 static names) ----
    f16x8 b0[8], b1[8];
    ldB(cbhq, 0, l15, lg, b0);
    for (int Nt = 0; Nt < 64; Nt += 2) {
      // prefetch Nt+1 while computing Nt
      ldB(cbhq, Nt + 1, l15, lg, b1);
      {
        const int n = Nt * 16 + l15;
        f32x4 accH = {0.f, 0.f, 0.f, 0.f}, accL = {0.f, 0.f, 0.f, 0.f};
#pragma unroll
        for (int ks = 0; ks < 8; ++ks) {
          accH = __builtin_amdgcn_mfma_f32_16x16x32_f16(Ah[ks], b0[ks], accH, 0, 0, 0);
          accL = __builtin_amdgcn_mfma_f32_16x16x32_f16(Al[ks], b0[ks], accL, 0, 0, 0);
        }
        float c2 = cnq[n];
#pragma unroll
        for (int r = 0; r < 4; ++r) {
          float s = c2 - 2.f * (accH[r] + accL[r]);
          ins3(tv[r], tk[r], s, n);
        }
      }
      // prefetch Nt+2 while computing Nt+1
      if (Nt + 2 < 64) ldB(cbhq, Nt + 2, l15, lg, b0);
      {
        const int n = (Nt + 1) * 16 + l15;
        f32x4 accH = {0.f, 0.f, 0.f, 0.f}, accL = {0.f, 0.f, 0.f, 0.f};
#pragma unroll
        for (int ks = 0; ks < 8; ++ks) {
          accH = __builtin_amdgcn_mfma_f32_16x16x32_f16(Ah[ks], b1[ks], accH, 0, 0, 0);
          accL = __builtin_amdgcn_mfma_f32_16x16x32_f16(Al[ks], b1[ks], accL, 0, 0, 0);
        }
        float c2 = cnq[n];
#pragma unroll
        for (int r = 0; r < 4; ++r) {
          float s = c2 - 2.f * (accH[r] + accL[r]);
          ins3(tv[r], tk[r], s, n);
        }
      }
    }

    // ---- merge top-3 across the 16 l15 lanes ------------------------------
#pragma unroll
    for (int r = 0; r < 4; ++r) {
#pragma unroll
      for (int off = 1; off < 16; off <<= 1) {
        float ov[3]; int ok[3];
#pragma unroll
        for (int i = 0; i < 3; ++i) {
          ov[i] = __shfl_xor(tv[r][i], off);
          ok[i] = __shfl_xor(tk[r][i], off);
        }
#pragma unroll
        for (int i = 0; i < 3; ++i) ins3(tv[r], tk[r], ov[i], ok[i]);
      }
    }

    // ---- leaders adjudicate + write indices -------------------------------
    if (l15 == 0) {
#pragma unroll
      for (int r = 0; r < 4; ++r) {
        int t = wv * 16 + lg * 4 + r;     // local token
        int kk = tk[r][0] & (K_ - 1);
        if (tv[r][1] - tv[r][0] < MARGIN_MFMA) {
          const float* rsrow = &rs[t * 256];
          float A = np_sum256([&](int d) {
            float rr = rsrow[d]; return __fmul_rn(rr, rr);
          });
          int cand[3]; int ncand = 1;
          cand[0] = kk;
          cand[ncand++] = tk[r][1] & (K_ - 1);
          if (tv[r][2] - tv[r][0] < MARGIN_MFMA) cand[ncand++] = tk[r][2] & (K_ - 1);
          float bd = 3.4e38f; int bk2 = 0x7FFFFFFF;
          for (int i = 0; i < ncand; ++i) {
            const float* crow = cbq + (size_t)cand[i] * D_;
            float E = np_einsum256([&](int d) {
              return __fmul_rn(rsrow[d], crow[d]);
            });
            float C = np_sum256([&](int d) {
              float cc = crow[d]; return __fmul_rn(cc, cc);
            });
            float dd = __fadd_rn(__fsub_rn(A, __fmul_rn(2.f, E)), C);
            if (dd < bd || (dd == bd && cand[i] < bk2)) { bd = dd; bk2 = cand[i]; }
          }
          kk = bk2;
        }
        bestk[t] = kk;
        out[QUANT_N + q * NTOK + tok0 + t] = (float)kk;
      }
    }
    __syncthreads();          // bestk visible; rs reads (A/adjudicate) done

    // ---- residual update + loss -------------------------------------------
    {
      int kk = bestk[ut] & (K_ - 1);
      const float* crow = cbq + (size_t)kk * D_;
#pragma unroll
      for (int j = 0; j < 16; ++j) {
        int c4 = j * 4 + uc;
        float4 cv = *(const float4*)&crow[c4 * 4];
        float4 rv = *(float4*)&rs[ut * 256 + c4 * 4];
        rv.x -= cv.x; rv.y -= cv.y; rv.z -= cv.z; rv.w -= cv.w;
        *(float4*)&rs[ut * 256 + c4 * 4] = rv;
        lsq += rv.x * rv.x + rv.y * rv.y + rv.z * rv.z + rv.w * rv.w;
      }
    }
    __syncthreads();          // rs updated before next stage's A-read
  }

  // ---- quant = x - r_final -------------------------------------------------
#pragma unroll
  for (int j = 0; j < 16; ++j) {
    int c4 = j * 4 + uc;
    float4 xv = *(const float4*)&x[(size_t)(tok0 + ut) * D_ + c4 * 4];
    float4 rv = *(const float4*)&rs[ut * 256 + c4 * 4];
    float4 o;
    o.x = xv.x - rv.x; o.y = xv.y - rv.y;
    o.z = xv.z - rv.z; o.w = xv.w - rv.w;
    *(float4*)&out[(size_t)(tok0 + ut) * D_ + c4 * 4] = o;
  }

  // ---- loss: wave reduce + one atomic per wave -----------------------------
#pragma unroll
  for (int off = 32; off; off >>= 1) lsq += __shfl_xor(lsq, off);
  if ((tid & 63) == 0) atomicAdd(loss_ws, lsq);
}

// ---------------------------------------------------------------------------
// FALLBACK (round-8 kernel, verbatim): used only if ws is too small for cbh.
__global__ __launch_bounds__(256) void rvq_cnorm(const float* __restrict__ cb,
                                                 float* __restrict__ cn) {
  int k = blockIdx.x * 4 + (threadIdx.x >> 6);
  int l = threadIdx.x & 63;
  const float* row = cb + (size_t)k * D_;
  float s = 0.f;
#pragma unroll
  for (int j = 0; j < 4; ++j) { float v = row[l + 64 * j]; s += v * v; }
#pragma unroll
  for (int off = 32; off; off >>= 1) s += __shfl_xor(s, off);
  if (l == 0) cn[k] = s;
}

__global__ __launch_bounds__(256, 2) void rvq_main_v8(const float* __restrict__ x,
                                                      const float* __restrict__ cb,
                                                      const float* __restrict__ cn,
                                                      float* __restrict__ out,
                                                      float* __restrict__ loss_ws) {
  __shared__ float4 rs4[32 * 64];
  __shared__ float4 cbt[64 * 16];
  __shared__ int bestk[32];
  const int tid  = threadIdx.x;
  const int tok0 = blockIdx.x * 32;
  const int ut = tid >> 3, uc = tid & 7;
  const int ty = tid >> 4, tx = tid & 15;
  const int t0 = ty * 2;
#pragma unroll
  for (int j = 0; j < 8; ++j) {
    int c4 = uc * 8 + j;
    float4 v = *(const float4*)&x[(size_t)(tok0 + ut) * D_ + c4 * 4];
    rs4[ut * 64 + (c4 ^ ((ut >> 2) & 3))] = v;
  }
  __syncthreads();
  float lsq = 0.f;
  for (int q = 0; q < Q_; ++q) {
    const float* cbq = cb + (size_t)q * K_ * D_;
    const float* cnq = cn + q * K_;
    float v1[2], v2[2]; int k1[2], k2[2];
#pragma unroll
    for (int i = 0; i < 2; ++i) { v1[i] = v2[i] = 3.4e38f; k1[i] = k2[i] = 0x7FFFFFFF; }
    for (int nc = 0; nc < 16; ++nc) {
      float acc[2][4];
#pragma unroll
      for (int i = 0; i < 2; ++i)
#pragma unroll
        for (int j = 0; j < 4; ++j) acc[i][j] = 0.f;
      for (int dc = 0; dc < 4; ++dc) {
        __syncthreads();
#pragma unroll
        for (int i = 0; i < 4; ++i) {
          int f = i * 256 + tid;
          int row = f >> 4, c = f & 15;
          float4 v = *(const float4*)&cbq[(size_t)(nc * 64 + row) * D_ + dc * 64 + c * 4];
          cbt[row * 16 + (c ^ (row >> 2))] = v;
        }
        __syncthreads();
#pragma unroll
        for (int d4 = 0; d4 < 16; ++d4) {
          float4 a[2], b[4];
#pragma unroll
          for (int i = 0; i < 2; ++i) {
            int t = t0 + i;
            int c4 = dc * 16 + d4;
            a[i] = rs4[t * 64 + (c4 ^ ((t >> 2) & 3))];
          }
#pragma unroll
          for (int j = 0; j < 4; ++j) {
            int row = tx * 4 + j;
            b[j] = cbt[row * 16 + (d4 ^ tx)];
          }
#pragma unroll
          for (int i = 0; i < 2; ++i)
#pragma unroll
            for (int j = 0; j < 4; ++j)
              acc[i][j] += a[i].x * b[j].x + a[i].y * b[j].y +
                           a[i].z * b[j].z + a[i].w * b[j].w;
        }
      }
#pragma unroll
      for (int j = 0; j < 4; ++j) {
        int k = nc * 64 + tx * 4 + j;
        float c2 = cnq[k];
#pragma unroll
        for (int i = 0; i < 2; ++i) {
          float s = c2 - 2.f * acc[i][j];
          if (lt2(s, k, v1[i], k1[i])) { v2[i] = v1[i]; k2[i] = k1[i]; v1[i] = s; k1[i] = k; }
          else if (lt2(s, k, v2[i], k2[i])) { v2[i] = s; k2[i] = k; }
        }
      }
    }
#pragma unroll
    for (int i = 0; i < 2; ++i) {
      float a1 = v1[i]; int b1 = k1[i];
      float a2 = v2[i]; int b2 = k2[i];
#pragma unroll
      for (int off = 1; off < 16; off <<= 1) {
        float o1 = __shfl_xor(a1, off); int p1 = __shfl_xor(b1, off);
        float o2 = __shfl_xor(a2, off); int p2 = __shfl_xor(b2, off);
        if (lt2(o1, p1, a1, b1)) {
          if (lt2(a1, b1, o2, p2)) { a2 = a1; b2 = b1; } else { a2 = o2; b2 = p2; }
          a1 = o1; b1 = p1;
        } else if (lt2(o1, p1, a2, b2)) { a2 = o1; b2 = p1; }
      }
      if (tx == 0) {
        int t = t0 + i;
        int kk = b1 & (K_ - 1);
        if (a2 - a1 < MARGIN_V8) {
          int kb = b2 & (K_ - 1);
          const float* rowA = cbq + (size_t)kk * D_;
          const float* rowB = cbq + (size_t)kb * D_;
          const float* rsf = (const float*)rs4;
          const int tt = t;
          auto rd = [&](int d) -> float {
            return rsf[(tt * 64 + ((d >> 2) ^ ((tt >> 2) & 3))) * 4 + (d & 3)];
          };
          float A  = np_sum256([&](int d) { float r = rd(d); return __fmul_rn(r, r); });
          float Ea = np_einsum256([&](int d) { return __fmul_rn(rd(d), rowA[d]); });
          float Ca = np_sum256([&](int d) { float c = rowA[d]; return __fmul_rn(c, c); });
          float Eb = np_einsum256([&](int d) { return __fmul_rn(rd(d), rowB[d]); });
          float Cb = np_sum256([&](int d) { float c = rowB[d]; return __fmul_rn(c, c); });
          float da = __fadd_rn(__fsub_rn(A, __fmul_rn(2.f, Ea)), Ca);
          float db = __fadd_rn(__fsub_rn(A, __fmul_rn(2.f, Eb)), Cb);
          if (db < da || (db == da && kb < kk)) kk = kb;
        }
        bestk[t] = kk;
        out[QUANT_N + q * NTOK + tok0 + t] = (float)kk;
      }
    }
    __syncthreads();
    {
      int kk = bestk[ut] & (K_ - 1);
      const float* crow = cbq + (size_t)kk * D_;
#pragma unroll
      for (int j = 0; j < 8; ++j) {
        int c4 = uc * 8 + j;
        float4 cv = *(const float4*)&crow[c4 * 4];
        int slot = ut * 64 + (c4 ^ ((ut >> 2) & 3));
        float4 rv = rs4[slot];
        rv.x -= cv.x; rv.y -= cv.y; rv.z -= cv.z; rv.w -= cv.w;
        rs4[slot] = rv;
        lsq += rv.x * rv.x + rv.y * rv.y + rv.z * rv.z + rv.w * rv.w;
      }
    }
  }
  __syncthreads();
#pragma unroll
  for (int j = 0; j < 8; ++j) {
    int c4 = uc * 8 + j;
    float4 xv = *(const float4*)&x[(size_t)(tok0 + ut) * D_ + c4 * 4];
    float4 rv = rs4[ut * 64 + (c4 ^ ((ut >> 2) & 3))];
    float4 o;
    o.x = xv.x - rv.x; o.y = xv.y - rv.y;
    o.z = xv.z - rv.z; o.w = xv.w - rv.w;
    *(float4*)&out[(size_t)(tok0 + ut) * D_ + c4 * 4] = o;
  }
#pragma unroll
  for (int off = 32; off; off >>= 1) lsq += __shfl_xor(lsq, off);
  if ((tid & 63) == 0) atomicAdd(loss_ws, lsq);
}

// ---------------------------------------------------------------------------
__global__ void rvq_finalize(const float* __restrict__ ws,
                             float* __restrict__ out) {
  if (threadIdx.x == 0) {
    float loss = 1.25f * ws[0] * (1.0f / (float)QUANT_N);
#pragma unroll
    for (int i = 0; i < 4; ++i) out[LOSS_OFF + i] = loss;
  }
}

// ---------------------------------------------------------------------------
extern "C" void kernel_launch(void* const* d_in, const int* in_sizes, int n_in,
                              void* d_out, int out_size, void* d_ws, size_t ws_size,
                              hipStream_t stream) {
  const float* x  = (const float*)d_in[0];
  const float* cb = (const float*)d_in[1];
  if (n_in >= 2 && in_sizes[0] != QUANT_N) {
    x  = (const float*)d_in[1];
    cb = (const float*)d_in[0];
  }
  float* out = (float*)d_out;

  float* ws = (float*)d_ws;
  float* cn = ws + 64;                                  // 4096 f32
  _Float16* cbh = (_Float16*)(ws + 64 + Q_ * K_);       // 2 MB fp16 codebook
  size_t need = (size_t)(64 + Q_ * K_) * 4 + (size_t)Q_ * K_ * D_ * 2 + 256;

  rvq_zero<<<1, 1, 0, stream>>>(ws);
  if (ws_size >= need) {
    rvq_prep<<<Q_ * K_ / 4, 256, 0, stream>>>(cb, cn, cbh);
    rvq_mfma<<<NTOK / 64, 256, 0, stream>>>(x, cb, cn, cbh, out, ws);
  } else {
    rvq_cnorm<<<Q_ * K_ / 4, 256, 0, stream>>>(cb, cn);
    rvq_main_v8<<<NTOK / 32, 256, 0, stream>>>(x, cb, cn, out, ws);
  }
  rvq_finalize<<<1, 64, 0, stream>>>(ws, out);
}

// Round 11
// 567.401 us; speedup vs baseline: 3.3941x; 1.0943x over previous
//
#include <hip/hip_runtime.h>

// RVQTokenizer: x[16,2048,256] f32, codebooks[4,1024,256] f32.
// Outputs (flat f32): quant[16,2048,256], indices[4,16,2048] (as float),
// 4 scalar losses (all = total vq_loss).
#define B_    16
#define T_    2048
#define D_    256
#define Q_    4
#define K_    1024
#define NTOK  (B_ * T_)            // 32768
#define QUANT_N (NTOK * D_)        // 8388608
#define IDX_N   (Q_ * NTOK)        // 131072
#define LOSS_OFF (QUANT_N + IDX_N) // 8519680
#define MARGIN_MFMA 0.06f          // fp16-coarse ambiguity window
#define MARGIN_V8   0.03f          // fp32-coarse window (fallback kernel)

typedef __attribute__((ext_vector_type(8))) _Float16 f16x8;
typedef __attribute__((ext_vector_type(4))) _Float16 f16x4;
typedef __attribute__((ext_vector_type(4))) float    f32x4;

__device__ __forceinline__ bool lt2(float v, int k, float w, int m) {
  return v < w || (v == w && k < m);
}

// ---------------------------------------------------------------------------
// Bit-exact numpy emulation (verified PASS in rounds 8-10).
template <typename F>
__device__ __forceinline__ float np_sum256(F p) {
  float half[2];
#pragma unroll
  for (int h = 0; h < 2; ++h) {
    const int base = h * 128;
    float s[16];
#pragma unroll
    for (int l = 0; l < 16; ++l) {
      float t01 = __fadd_rn(p(base + l),      p(base + 16 + l));
      float t23 = __fadd_rn(p(base + 32 + l), p(base + 48 + l));
      float t45 = __fadd_rn(p(base + 64 + l), p(base + 80 + l));
      float t67 = __fadd_rn(p(base + 96 + l), p(base + 112 + l));
      s[l] = __fadd_rn(__fadd_rn(t01, t23), __fadd_rn(t45, t67));
    }
#pragma unroll
    for (int w = 8; w >= 1; w >>= 1)
#pragma unroll
      for (int l = 0; l < w; ++l) s[l] = __fadd_rn(s[l], s[l + w]);
    half[h] = s[0];
  }
  return __fadd_rn(half[0], half[1]);
}

template <typename F>
__device__ __forceinline__ float np_einsum256(F p) {
  float v[4] = {0.f, 0.f, 0.f, 0.f};
#pragma unroll
  for (int c = 0; c < 16; ++c) {
#pragma unroll
    for (int l = 0; l < 4; ++l) {
      int d0 = c * 16 + l;
      float t = __fadd_rn(p(d0 + 12), v[l]);
      t = __fadd_rn(p(d0 + 8), t);
      t = __fadd_rn(p(d0 + 4), t);
      v[l] = __fadd_rn(p(d0), t);
    }
  }
  return __fadd_rn(__fadd_rn(v[0], v[1]), __fadd_rn(v[2], v[3]));
}

__global__ void rvq_zero(float* __restrict__ ws) { ws[0] = 0.f; }

// ---------------------------------------------------------------------------
// Prep: cn[k]=||c_k||^2 (coarse only) and fp16 codebook copy.
__global__ __launch_bounds__(256) void rvq_prep(const float* __restrict__ cb,
                                                float* __restrict__ cn,
                                                _Float16* __restrict__ cbh) {
  int k = blockIdx.x * 4 + (threadIdx.x >> 6);   // 0..4095
  int l = threadIdx.x & 63;
  const float* row = cb + (size_t)k * D_;
  float s = 0.f;
#pragma unroll
  for (int j = 0; j < 4; ++j) { float v = row[l + 64 * j]; s += v * v; }
#pragma unroll
  for (int off = 32; off; off >>= 1) s += __shfl_xor(s, off);
  if (l == 0) cn[k] = s;
  int gid = blockIdx.x * 256 + threadIdx.x;      // 0..262143
  float4 v = *(const float4*)&cb[(size_t)gid * 4];
  f16x4 h;
  h[0] = (_Float16)v.x; h[1] = (_Float16)v.y;
  h[2] = (_Float16)v.z; h[3] = (_Float16)v.w;
  *(f16x4*)&cbh[(size_t)gid * 4] = h;
}

__device__ __forceinline__ void ins3(float* tv, int* tk, float v, int k) {
  if (lt2(v, k, tv[0], tk[0])) {
    tv[2] = tv[1]; tk[2] = tk[1]; tv[1] = tv[0]; tk[1] = tk[0];
    tv[0] = v; tk[0] = k;
  } else if (lt2(v, k, tv[1], tk[1])) {
    tv[2] = tv[1]; tk[2] = tk[1]; tv[1] = v; tk[1] = k;
  } else if (lt2(v, k, tv[2], tk[2])) {
    tv[2] = v; tk[2] = k;
  }
}

// load B fragments for codeword group Nt (8 x f16x8 per lane)
__device__ __forceinline__ void ldB(const _Float16* __restrict__ cbhq,
                                    int Nt, int l15, int lg, f16x8* bb) {
  const _Float16* brow = cbhq + (size_t)(Nt * 16 + l15) * D_ + lg * 8;
#pragma unroll
  for (int ks = 0; ks < 8; ++ks) bb[ks] = *(const f16x8*)&brow[ks * 32];
}

// score one codeword group from buffer bb: 4 independent MFMA chains of 4.
#define SCORE_GRP(bb, grp)                                                    \
  do {                                                                        \
    const int n_ = (grp) * 16 + l15;                                          \
    f32x4 h0 = {0.f,0.f,0.f,0.f}, h1 = {0.f,0.f,0.f,0.f};                     \
    f32x4 l0 = {0.f,0.f,0.f,0.f}, l1 = {0.f,0.f,0.f,0.f};                     \
    _Pragma("unroll")                                                         \
    for (int ks = 0; ks < 4; ++ks) {                                          \
      h0 = __builtin_amdgcn_mfma_f32_16x16x32_f16(Ah[ks],     bb[ks],     h0, 0, 0, 0); \
      h1 = __builtin_amdgcn_mfma_f32_16x16x32_f16(Ah[ks + 4], bb[ks + 4], h1, 0, 0, 0); \
      l0 = __builtin_amdgcn_mfma_f32_16x16x32_f16(Al[ks],     bb[ks],     l0, 0, 0, 0); \
      l1 = __builtin_amdgcn_mfma_f32_16x16x32_f16(Al[ks + 4], bb[ks + 4], l1, 0, 0, 0); \
    }                                                                         \
    float c2_ = cnq[n_];                                                      \
    _Pragma("unroll")                                                         \
    for (int r = 0; r < 4; ++r) {                                             \
      float s_ = c2_ - 2.f * ((h0[r] + h1[r]) + (l0[r] + l1[r]));             \
      ins3(tv[r], tk[r], s_, n_);                                             \
    }                                                                         \
  } while (0)

// ---------------------------------------------------------------------------
// MFMA RVQ. 64 tokens/block, 256 threads (4 waves, 1 M-tile each).
// B-panel loads pipelined 2 groups ahead (b0/b1/b2 static rotation).
__global__ __launch_bounds__(256, 2) void rvq_mfma(const float* __restrict__ x,
                                                   const float* __restrict__ cb,
                                                   const float* __restrict__ cn,
                                                   const _Float16* __restrict__ cbh,
                                                   float* __restrict__ out,
                                                   float* __restrict__ loss_ws) {
  __shared__ float rs[64 * 256];   // 64 KiB, linear [t][d]
  __shared__ int bestk[64];

  const int tid  = threadIdx.x;
  const int tok0 = blockIdx.x * 64;
  const int lane = tid & 63;
  const int wv   = tid >> 6;       // wave id = M-tile (tokens wv*16..+15)
  const int l15  = lane & 15;      // A-row / B-col / D-col index
  const int lg   = lane >> 4;      // k-group / D-row-group
  const int ut   = tid >> 2, uc = tid & 3;   // streaming: 4 threads per token

  // ---- load x -> rs -------------------------------------------------------
#pragma unroll
  for (int j = 0; j < 16; ++j) {
    int c4 = j * 4 + uc;
    *(float4*)&rs[ut * 256 + c4 * 4] =
        *(const float4*)&x[(size_t)(tok0 + ut) * D_ + c4 * 4];
  }
  __syncthreads();

  float lsq = 0.f;

  for (int q = 0; q < Q_; ++q) {
    const float*    cbq  = cb  + (size_t)q * K_ * D_;
    const float*    cnq  = cn  + q * K_;
    const _Float16* cbhq = cbh + (size_t)q * K_ * D_;

    // ---- A fragments (fp16 hi/lo) for this wave's 16 token rows ----------
    f16x8 Ah[8], Al[8];
    {
      const float* rrow = &rs[(wv * 16 + l15) * 256];
#pragma unroll
      for (int ks = 0; ks < 8; ++ks) {
        float4 v0 = *(const float4*)&rrow[ks * 32 + lg * 8];
        float4 v1 = *(const float4*)&rrow[ks * 32 + lg * 8 + 4];
        float vv[8] = {v0.x, v0.y, v0.z, v0.w, v1.x, v1.y, v1.z, v1.w};
        f16x8 h, l;
#pragma unroll
        for (int j = 0; j < 8; ++j) {
          _Float16 hj = (_Float16)vv[j];
          h[j] = hj;
          l[j] = (_Float16)(vv[j] - (float)hj);
        }
        Ah[ks] = h; Al[ks] = l;
      }
    }

    // ---- top-3 state: tokens m = wv*16 + lg*4 + r -------------------------
    float tv[4][3]; int tk[4][3];
#pragma unroll
    for (int r = 0; r < 4; ++r)
#pragma unroll
      for (int i = 0; i < 3; ++i) { tv[r][i] = 3.4e38f; tk[r][i] = 0x7FFFFFFF; }

    // ---- coarse scoring, 2-deep pipeline (b0/b1/b2 static rotation) -------
    {
      f16x8 b0[8], b1[8], b2[8];
      ldB(cbhq, 0, l15, lg, b0);
      ldB(cbhq, 1, l15, lg, b1);
      for (int p = 0; p < 21; ++p) {        // groups 3p, 3p+1, 3p+2
        const int g = 3 * p;
        ldB(cbhq, g + 2, l15, lg, b2);
        SCORE_GRP(b0, g);
        if (g + 3 < 64) ldB(cbhq, g + 3, l15, lg, b0);
        SCORE_GRP(b1, g + 1);
        if (g + 4 < 64) ldB(cbhq, g + 4, l15, lg, b1);
        SCORE_GRP(b2, g + 2);
      }
      SCORE_GRP(b0, 63);                    // loaded at p=20 (3*20+3)
    }

    // ---- merge top-3 across the 16 l15 lanes ------------------------------
#pragma unroll
    for (int r = 0; r < 4; ++r) {
#pragma unroll
      for (int off = 1; off < 16; off <<= 1) {
        float ov[3]; int ok[3];
#pragma unroll
        for (int i = 0; i < 3; ++i) {
          ov[i] = __shfl_xor(tv[r][i], off);
          ok[i] = __shfl_xor(tk[r][i], off);
        }
#pragma unroll
        for (int i = 0; i < 3; ++i) ins3(tv[r], tk[r], ov[i], ok[i]);
      }
    }

    // ---- leaders adjudicate + write indices -------------------------------
    if (l15 == 0) {
#pragma unroll
      for (int r = 0; r < 4; ++r) {
        int t = wv * 16 + lg * 4 + r;     // local token
        int kk = tk[r][0] & (K_ - 1);
        if (tv[r][1] - tv[r][0] < MARGIN_MFMA) {
          const float* rsrow = &rs[t * 256];
          float A = np_sum256([&](int d) {
            float rr = rsrow[d]; return __fmul_rn(rr, rr);
          });
          int cand[3]; int ncand = 1;
          cand[0] = kk;
          cand[ncand++] = tk[r][1] & (K_ - 1);
          if (tv[r][2] - tv[r][0] < MARGIN_MFMA) cand[ncand++] = tk[r][2] & (K_ - 1);
          float bd = 3.4e38f; int bk2 = 0x7FFFFFFF;
          for (int i = 0; i < ncand; ++i) {
            const float* crow = cbq + (size_t)cand[i] * D_;
            float E = np_einsum256([&](int d) {
              return __fmul_rn(rsrow[d], crow[d]);
            });
            float C = np_sum256([&](int d) {
              float cc = crow[d]; return __fmul_rn(cc, cc);
            });
            float dd = __fadd_rn(__fsub_rn(A, __fmul_rn(2.f, E)), C);
            if (dd < bd || (dd == bd && cand[i] < bk2)) { bd = dd; bk2 = cand[i]; }
          }
          kk = bk2;
        }
        bestk[t] = kk;
        out[QUANT_N + q * NTOK + tok0 + t] = (float)kk;
      }
    }
    __syncthreads();          // bestk visible; rs reads (A/adjudicate) done

    // ---- residual update + loss -------------------------------------------
    {
      int kk = bestk[ut] & (K_ - 1);
      const float* crow = cbq + (size_t)kk * D_;
#pragma unroll
      for (int j = 0; j < 16; ++j) {
        int c4 = j * 4 + uc;
        float4 cv = *(const float4*)&crow[c4 * 4];
        float4 rv = *(float4*)&rs[ut * 256 + c4 * 4];
        rv.x -= cv.x; rv.y -= cv.y; rv.z -= cv.z; rv.w -= cv.w;
        *(float4*)&rs[ut * 256 + c4 * 4] = rv;
        lsq += rv.x * rv.x + rv.y * rv.y + rv.z * rv.z + rv.w * rv.w;
      }
    }
    __syncthreads();          // rs updated before next stage's A-read
  }

  // ---- quant = x - r_final -------------------------------------------------
#pragma unroll
  for (int j = 0; j < 16; ++j) {
    int c4 = j * 4 + uc;
    float4 xv = *(const float4*)&x[(size_t)(tok0 + ut) * D_ + c4 * 4];
    float4 rv = *(const float4*)&rs[ut * 256 + c4 * 4];
    float4 o;
    o.x = xv.x - rv.x; o.y = xv.y - rv.y;
    o.z = xv.z - rv.z; o.w = xv.w - rv.w;
    *(float4*)&out[(size_t)(tok0 + ut) * D_ + c4 * 4] = o;
  }

  // ---- loss: wave reduce + one atomic per wave -----------------------------
#pragma unroll
  for (int off = 32; off; off >>= 1) lsq += __shfl_xor(lsq, off);
  if ((tid & 63) == 0) atomicAdd(loss_ws, lsq);
}

// ---------------------------------------------------------------------------
// FALLBACK (round-8 kernel, verbatim): used only if ws is too small for cbh.
__global__ __launch_bounds__(256) void rvq_cnorm(const float* __restrict__ cb,
                                                 float* __restrict__ cn) {
  int k = blockIdx.x * 4 + (threadIdx.x >> 6);
  int l = threadIdx.x & 63;
  const float* row = cb + (size_t)k * D_;
  float s = 0.f;
#pragma unroll
  for (int j = 0; j < 4; ++j) { float v = row[l + 64 * j]; s += v * v; }
#pragma unroll
  for (int off = 32; off; off >>= 1) s += __shfl_xor(s, off);
  if (l == 0) cn[k] = s;
}

__global__ __launch_bounds__(256, 2) void rvq_main_v8(const float* __restrict__ x,
                                                      const float* __restrict__ cb,
                                                      const float* __restrict__ cn,
                                                      float* __restrict__ out,
                                                      float* __restrict__ loss_ws) {
  __shared__ float4 rs4[32 * 64];
  __shared__ float4 cbt[64 * 16];
  __shared__ int bestk[32];
  const int tid  = threadIdx.x;
  const int tok0 = blockIdx.x * 32;
  const int ut = tid >> 3, uc = tid & 7;
  const int ty = tid >> 4, tx = tid & 15;
  const int t0 = ty * 2;
#pragma unroll
  for (int j = 0; j < 8; ++j) {
    int c4 = uc * 8 + j;
    float4 v = *(const float4*)&x[(size_t)(tok0 + ut) * D_ + c4 * 4];
    rs4[ut * 64 + (c4 ^ ((ut >> 2) & 3))] = v;
  }
  __syncthreads();
  float lsq = 0.f;
  for (int q = 0; q < Q_; ++q) {
    const float* cbq = cb + (size_t)q * K_ * D_;
    const float* cnq = cn + q * K_;
    float v1[2], v2[2]; int k1[2], k2[2];
#pragma unroll
    for (int i = 0; i < 2; ++i) { v1[i] = v2[i] = 3.4e38f; k1[i] = k2[i] = 0x7FFFFFFF; }
    for (int nc = 0; nc < 16; ++nc) {
      float acc[2][4];
#pragma unroll
      for (int i = 0; i < 2; ++i)
#pragma unroll
        for (int j = 0; j < 4; ++j) acc[i][j] = 0.f;
      for (int dc = 0; dc < 4; ++dc) {
        __syncthreads();
#pragma unroll
        for (int i = 0; i < 4; ++i) {
          int f = i * 256 + tid;
          int row = f >> 4, c = f & 15;
          float4 v = *(const float4*)&cbq[(size_t)(nc * 64 + row) * D_ + dc * 64 + c * 4];
          cbt[row * 16 + (c ^ (row >> 2))] = v;
        }
        __syncthreads();
#pragma unroll
        for (int d4 = 0; d4 < 16; ++d4) {
          float4 a[2], b[4];
#pragma unroll
          for (int i = 0; i < 2; ++i) {
            int t = t0 + i;
            int c4 = dc * 16 + d4;
            a[i] = rs4[t * 64 + (c4 ^ ((t >> 2) & 3))];
          }
#pragma unroll
          for (int j = 0; j < 4; ++j) {
            int row = tx * 4 + j;
            b[j] = cbt[row * 16 + (d4 ^ tx)];
          }
#pragma unroll
          for (int i = 0; i < 2; ++i)
#pragma unroll
            for (int j = 0; j < 4; ++j)
              acc[i][j] += a[i].x * b[j].x + a[i].y * b[j].y +
                           a[i].z * b[j].z + a[i].w * b[j].w;
        }
      }
#pragma unroll
      for (int j = 0; j < 4; ++j) {
        int k = nc * 64 + tx * 4 + j;
        float c2 = cnq[k];
#pragma unroll
        for (int i = 0; i < 2; ++i) {
          float s = c2 - 2.f * acc[i][j];
          if (lt2(s, k, v1[i], k1[i])) { v2[i] = v1[i]; k2[i] = k1[i]; v1[i] = s; k1[i] = k; }
          else if (lt2(s, k, v2[i], k2[i])) { v2[i] = s; k2[i] = k; }
        }
      }
    }
#pragma unroll
    for (int i = 0; i < 2; ++i) {
      float a1 = v1[i]; int b1 = k1[i];
      float a2 = v2[i]; int b2 = k2[i];
#pragma unroll
      for (int off = 1; off < 16; off <<= 1) {
        float o1 = __shfl_xor(a1, off); int p1 = __shfl_xor(b1, off);
        float o2 = __shfl_xor(a2, off); int p2 = __shfl_xor(b2, off);
        if (lt2(o1, p1, a1, b1)) {
          if (lt2(a1, b1, o2, p2)) { a2 = a1; b2 = b1; } else { a2 = o2; b2 = p2; }
          a1 = o1; b1 = p1;
        } else if (lt2(o1, p1, a2, b2)) { a2 = o1; b2 = p1; }
      }
      if (tx == 0) {
        int t = t0 + i;
        int kk = b1 & (K_ - 1);
        if (a2 - a1 < MARGIN_V8) {
          int kb = b2 & (K_ - 1);
          const float* rowA = cbq + (size_t)kk * D_;
          const float* rowB = cbq + (size_t)kb * D_;
          const float* rsf = (const float*)rs4;
          const int tt = t;
          auto rd = [&](int d) -> float {
            return rsf[(tt * 64 + ((d >> 2) ^ ((tt >> 2) & 3))) * 4 + (d & 3)];
          };
          float A  = np_sum256([&](int d) { float r = rd(d); return __fmul_rn(r, r); });
          float Ea = np_einsum256([&](int d) { return __fmul_rn(rd(d), rowA[d]); });
          float Ca = np_sum256([&](int d) { float c = rowA[d]; return __fmul_rn(c, c); });
          float Eb = np_einsum256([&](int d) { return __fmul_rn(rd(d), rowB[d]); });
          float Cb = np_sum256([&](int d) { float c = rowB[d]; return __fmul_rn(c, c); });
          float da = __fadd_rn(__fsub_rn(A, __fmul_rn(2.f, Ea)), Ca);
          float db = __fadd_rn(__fsub_rn(A, __fmul_rn(2.f, Eb)), Cb);
          if (db < da || (db == da && kb < kk)) kk = kb;
        }
        bestk[t] = kk;
        out[QUANT_N + q * NTOK + tok0 + t] = (float)kk;
      }
    }
    __syncthreads();
    {
      int kk = bestk[ut] & (K_ - 1);
      const float* crow = cbq + (size_t)kk * D_;
#pragma unroll
      for (int j = 0; j < 8; ++j) {
        int c4 = uc * 8 + j;
        float4 cv = *(const float4*)&crow[c4 * 4];
        int slot = ut * 64 + (c4 ^ ((ut >> 2) & 3));
        float4 rv = rs4[slot];
        rv.x -= cv.x; rv.y -= cv.y; rv.z -= cv.z; rv.w -= cv.w;
        rs4[slot] = rv;
        lsq += rv.x * rv.x + rv.y * rv.y + rv.z * rv.z + rv.w * rv.w;
      }
    }
  }
  __syncthreads();
#pragma unroll
  for (int j = 0; j < 8; ++j) {
    int c4 = uc * 8 + j;
    float4 xv = *(const float4*)&x[(size_t)(tok0 + ut) * D_ + c4 * 4];
    float4 rv = rs4[ut * 64 + (c4 ^ ((ut >> 2) & 3))];
    float4 o;
    o.x = xv.x - rv.x; o.y = xv.y - rv.y;
    o.z = xv.z - rv.z; o.w = xv.w - rv.w;
    *(float4*)&out[(size_t)(tok0 + ut) * D_ + c4 * 4] = o;
  }
#pragma unroll
  for (int off = 32; off; off >>= 1) lsq += __shfl_xor(lsq, off);
  if ((tid & 63) == 0) atomicAdd(loss_ws, lsq);
}

// ---------------------------------------------------------------------------
__global__ void rvq_finalize(const float* __restrict__ ws,
                             float* __restrict__ out) {
  if (threadIdx.x == 0) {
    float loss = 1.25f * ws[0] * (1.0f / (float)QUANT_N);
#pragma unroll
    for (int i = 0; i < 4; ++i) out[LOSS_OFF + i] = loss;
  }
}

// ---------------------------------------------------------------------------
extern "C" void kernel_launch(void* const* d_in, const int* in_sizes, int n_in,
                              void* d_out, int out_size, void* d_ws, size_t ws_size,
                              hipStream_t stream) {
  const float* x  = (const float*)d_in[0];
  const float* cb = (const float*)d_in[1];
  if (n_in >= 2 && in_sizes[0] != QUANT_N) {
    x  = (const float*)d_in[1];
    cb = (const float*)d_in[0];
  }
  float* out = (float*)d_out;

  float* ws = (float*)d_ws;
  float* cn = ws + 64;                                  // 4096 f32
  _Float16* cbh = (_Float16*)(ws + 64 + Q_ * K_);       // 2 MB fp16 codebook
  size_t need = (size_t)(64 + Q_ * K_) * 4 + (size_t)Q_ * K_ * D_ * 2 + 256;

  rvq_zero<<<1, 1, 0, stream>>>(ws);
  if (ws_size >= need) {
    rvq_prep<<<Q_ * K_ / 4, 256, 0, stream>>>(cb, cn, cbh);
    rvq_mfma<<<NTOK / 64, 256, 0, stream>>>(x, cb, cn, cbh, out, ws);
  } else {
    rvq_cnorm<<<Q_ * K_ / 4, 256, 0, stream>>>(cb, cn);
    rvq_main_v8<<<NTOK / 32, 256, 0, stream>>>(x, cb, cn, out, ws);
  }
  rvq_finalize<<<1, 64, 0, stream>>>(ws, out);
}